// Round 8
// baseline (63.843 us; speedup 1.0000x reference)
//
#include <hip/hip_runtime.h>

#define BB 4
#define CIN 3
#define HH 512
#define WW 512
#define KK 9
#define COUT 3
#define HO 510
#define WO 510
#define HW (HH * WW)
#define HOWO (HO * WO)
#define NPX (BB * HOWO)

// padded NHWC buffer: rows -3..514, cols -3..516 -> [518][520], origin (3,3)
#define PR 518
#define PC 520
#define PAD 3
#define XP_BYTES ((size_t)BB * PR * PC * 4 * sizeof(float))
#define OFFSA_BYTES ((size_t)2 * NPX * sizeof(uint4))
#define OFFSB_BYTES ((size_t)NPX * sizeof(unsigned int))
#define WS_NEED (XP_BYTES + OFFSA_BYTES + OFFSB_BYTES)

typedef __fp16 h2 __attribute__((ext_vector_type(2)));

__device__ __forceinline__ h2 pkrtz(float a, float b) {
    return __builtin_amdgcn_cvt_pkrtz(a, b);
}
__device__ __forceinline__ float fdot2f(h2 a, h2 b, float c) {
    return __builtin_amdgcn_fdot2(a, b, c, false);
}
__device__ __forceinline__ h2 uint_as_h2(unsigned u) {
    return __builtin_bit_cast(h2, u);
}
__device__ __forceinline__ unsigned h2_as_uint(h2 h) {
    return __builtin_bit_cast(unsigned, h);
}
__device__ __forceinline__ float comp3(const float4& v, int c) {
    return c == 0 ? v.x : (c == 1 ? v.y : v.z);
}
// w1 element for channel ch at t2 = r*9 + s*3 + c (0 if t2 >= 27)
__device__ __forceinline__ float w1f(const float* w1, int ch, int t2) {
    if (t2 >= 27) return 0.f;
    const int r = t2 / 9, s = (t2 % 9) / 3, c = t2 % 3;
    return w1[ch * 27 + c * 9 + r * 3 + s];
}

// ---------------- kernel 1: NCHW -> padded NHW4 repack ----------------
__global__ __launch_bounds__(256) void repack_pad(
    const float* __restrict__ x, float4* __restrict__ xp)
{
    const int idx = blockIdx.x * blockDim.x + threadIdx.x;
    const int total = BB * PR * PC;
    if (idx >= total) return;
    const int b = idx / (PR * PC);
    const int rem = idx - b * (PR * PC);
    const int y = rem / PC;
    const int xc = rem - y * PC;
    const int ys = y - PAD;
    const int xs = xc - PAD;
    float4 v = make_float4(0.f, 0.f, 0.f, 0.f);
    if ((unsigned)ys < (unsigned)HH && (unsigned)xs < (unsigned)WW) {
        const float* xb = x + (size_t)b * CIN * HW;
        const int p = ys * WW + xs;
        v.x = xb[p];
        v.y = xb[HW + p];
        v.z = xb[2 * HW + p];
    }
    xp[idx] = v;
}

// ---------------- kernel 2: conv1 (fdot2) -> f16-packed offsets ------------
// offsA: 2 uint4 planes (taps 0-3, 4-7), offsB: 1 uint plane (tap 8).
// Each dword = pkrtz(dy, dx) for one tap.
__global__ __launch_bounds__(256) void conv1_off(
    const float4* __restrict__ xp,  // [B][PR][PC] padded NHWC
    const float* __restrict__ w1,   // [18][3][3][3]
    const float* __restrict__ b1,   // [18]
    uint4* __restrict__ offsA,      // [2][NPX]
    unsigned int* __restrict__ offsB)  // [NPX]
{
    __shared__ uint4 s_w1h[KK * 7];
    __shared__ float s_b[18];

    if (threadIdx.x < KK * 7) {
        const int k = threadIdx.x / 7;
        const int gg = threadIdx.x % 7;
        float wy[4], wx[4];
#pragma unroll
        for (int q = 0; q < 4; ++q) {
            const int t2 = 4 * gg + q;
            wy[q] = w1f(w1, 2 * k, t2);
            wx[q] = w1f(w1, 2 * k + 1, t2);
        }
        uint4 u;
        u.x = h2_as_uint(pkrtz(wy[0], wy[1]));
        u.y = h2_as_uint(pkrtz(wx[0], wx[1]));
        u.z = h2_as_uint(pkrtz(wy[2], wy[3]));
        u.w = h2_as_uint(pkrtz(wx[2], wx[3]));
        s_w1h[threadIdx.x] = u;
    }
    if (threadIdx.x < 18) s_b[threadIdx.x] = b1[threadIdx.x];
    __syncthreads();

    constexpr int WP = WO / 2;  // 255
    const int idx = blockIdx.x * 256 + threadIdx.x;
    if (idx >= BB * HO * WP) return;
    const int jp = idx % WP;
    const int t1 = idx / WP;
    const int i = t1 % HO;
    const int b = t1 / HO;
    const int j = jp * 2;
    const int pid = b * HOWO + i * WO + j;

    const float4* xb4 = xp + (size_t)b * (PR * PC);

    float4 pat[3][4];
#pragma unroll
    for (int r = 0; r < 3; ++r)
#pragma unroll
        for (int col = 0; col < 4; ++col)
            pat[r][col] = xb4[(i + r + PAD) * PC + (j + col + PAD)];

    // f16-pair packed patch per pixel over t2
    h2 ph0[14], ph1[14];
#pragma unroll
    for (int g = 0; g < 14; ++g) {
        const int ta = 2 * g;
        const int ra = ta / 9, sa = (ta % 9) / 3, ca = ta % 3;
        const float a0 = comp3(pat[ra][sa], ca);
        const float a1 = comp3(pat[ra][sa + 1], ca);
        float b0 = 0.f, b1v = 0.f;
        if (2 * g + 1 < 27) {
            const int tb = 2 * g + 1;
            const int rb = tb / 9, sb = (tb % 9) / 3, cb = tb % 3;
            b0 = comp3(pat[rb][sb], cb);
            b1v = comp3(pat[rb][sb + 1], cb);
        }
        ph0[g] = pkrtz(a0, b0);
        ph1[g] = pkrtz(a1, b1v);
    }

    unsigned pk0[KK], pk1[KK];  // packed (dy,dx) per tap, static-indexed
#pragma unroll
    for (int k = 0; k < KK; ++k) {
        float ay0 = 0.f, ax0 = 0.f, ay1 = 0.f, ax1 = 0.f;
        float by0 = 0.f, bx0 = 0.f, by1 = 0.f, bx1 = 0.f;
        const uint4* wk = &s_w1h[k * 7];
#pragma unroll
        for (int gg = 0; gg < 7; ++gg) {
            const uint4 w = wk[gg];
            const h2 wyA = uint_as_h2(w.x);
            const h2 wxA = uint_as_h2(w.y);
            const h2 wyB = uint_as_h2(w.z);
            const h2 wxB = uint_as_h2(w.w);
            ay0 = fdot2f(wyA, ph0[2 * gg], ay0);
            ax0 = fdot2f(wxA, ph0[2 * gg], ax0);
            ay1 = fdot2f(wyA, ph1[2 * gg], ay1);
            ax1 = fdot2f(wxA, ph1[2 * gg], ax1);
            by0 = fdot2f(wyB, ph0[2 * gg + 1], by0);
            bx0 = fdot2f(wxB, ph0[2 * gg + 1], bx0);
            by1 = fdot2f(wyB, ph1[2 * gg + 1], by1);
            bx1 = fdot2f(wxB, ph1[2 * gg + 1], bx1);
        }
        const float dy0 = s_b[2 * k] + (ay0 + by0);
        const float dx0 = s_b[2 * k + 1] + (ax0 + bx0);
        const float dy1 = s_b[2 * k] + (ay1 + by1);
        const float dx1 = s_b[2 * k + 1] + (ax1 + bx1);
        pk0[k] = h2_as_uint(pkrtz(dy0, dx0));
        pk1[k] = h2_as_uint(pkrtz(dy1, dx1));
    }

    offsA[pid]           = make_uint4(pk0[0], pk0[1], pk0[2], pk0[3]);
    offsA[pid + 1]       = make_uint4(pk1[0], pk1[1], pk1[2], pk1[3]);
    offsA[NPX + pid]     = make_uint4(pk0[4], pk0[5], pk0[6], pk0[7]);
    offsA[NPX + pid + 1] = make_uint4(pk1[4], pk1[5], pk1[6], pk1[7]);
    offsB[pid]     = pk0[8];
    offsB[pid + 1] = pk1[8];
}

// ---------------- kernel 3: bilinear gather + conv2, 1 px/thread -----------
__global__ __launch_bounds__(256) void deform_gather(
    const float4* __restrict__ xp,
    const uint4* __restrict__ offsA,
    const unsigned int* __restrict__ offsB,
    const float* __restrict__ w2,  // [3][3][3][3]
    const float* __restrict__ b2,  // [3]
    float* __restrict__ out)
{
    __shared__ float s_w2[KK * 12];  // [k][12], first 9 = o*3+c
    __shared__ float s_b2[COUT];
    for (int t = threadIdx.x; t < KK * 12; t += 256) {
        const int k = t / 12;
        const int q = t % 12;
        s_w2[t] = (q < 9) ? w2[(q / 3) * 27 + (q % 3) * 9 + k] : 0.f;
    }
    if (threadIdx.x < COUT) s_b2[threadIdx.x] = b2[threadIdx.x];
    __syncthreads();

    const int pid = blockIdx.x * 256 + threadIdx.x;
    if (pid >= NPX) return;
    const int j = pid % WO;
    const int t1 = pid / WO;
    const int i = t1 % HO;
    const int b = t1 / HO;

    const uint4 A0 = offsA[pid];
    const uint4 A1 = offsA[NPX + pid];
    const unsigned B8 = offsB[pid];

    const float4* xb4 = xp + (size_t)b * (PR * PC);
    const float fi3 = (float)i + (float)PAD;
    const float fj3 = (float)j + (float)PAD;

    float acc0 = s_b2[0], acc1 = s_b2[1], acc2 = s_b2[2];

#pragma unroll
    for (int k = 0; k < KK; ++k) {
        unsigned u;
        if (k == 0) u = A0.x;
        else if (k == 1) u = A0.y;
        else if (k == 2) u = A0.z;
        else if (k == 3) u = A0.w;
        else if (k == 4) u = A1.x;
        else if (k == 5) u = A1.y;
        else if (k == 6) u = A1.z;
        else if (k == 7) u = A1.w;
        else u = B8;

        const h2 d = uint_as_h2(u);
        const float dy = (float)d.x;
        const float dx = (float)d.y;
        const float syp = fi3 + (float)(k / 3) + dy;  // > 0 always
        const float sxp = fj3 + (float)(k % 3) + dx;
        const int y0 = (int)syp;  // trunc == floor (positive)
        const int x0 = (int)sxp;
        const float fy = syp - (float)y0;
        const float fx = sxp - (float)x0;

        const int a00 = y0 * PC + x0;
        const float4 c00 = xb4[a00];
        const float4 c01 = xb4[a00 + 1];
        const float4 c10 = xb4[a00 + PC];
        const float4 c11 = xb4[a00 + PC + 1];

        const float wy0 = 1.f - fy, wx0 = 1.f - fx;
        const float w00 = wy0 * wx0, w01 = wy0 * fx;
        const float w10 = fy * wx0, w11 = fy * fx;

        const float v0 = w00 * c00.x + w01 * c01.x + w10 * c10.x + w11 * c11.x;
        const float v1 = w00 * c00.y + w01 * c01.y + w10 * c10.y + w11 * c11.y;
        const float v2 = w00 * c00.z + w01 * c01.z + w10 * c10.z + w11 * c11.z;

        const float4* wk4 = reinterpret_cast<const float4*>(&s_w2[k * 12]);
        const float4 a = wk4[0];
        const float4 bbv = wk4[1];
        const float cw = s_w2[k * 12 + 8];
        acc0 += a.x * v0 + a.y * v1 + a.z * v2;
        acc1 += a.w * v0 + bbv.x * v1 + bbv.y * v2;
        acc2 += bbv.z * v0 + bbv.w * v1 + cw * v2;
    }

    float* ob = out + (size_t)b * COUT * HOWO + (size_t)i * WO + j;
    ob[0 * HOWO] = acc0;
    ob[1 * HOWO] = acc1;
    ob[2 * HOWO] = acc2;
}

// ---------------- fallback: R0-style fully fused (no workspace) ----------
__global__ __launch_bounds__(256) void deform_fused_kernel(
    const float* __restrict__ x, const float* __restrict__ w1,
    const float* __restrict__ b1, const float* __restrict__ w2,
    const float* __restrict__ b2, float* __restrict__ out)
{
    __shared__ float s_w1[18 * 27];
    __shared__ float s_b1[18];
    __shared__ float s_w2[COUT * CIN * KK];
    __shared__ float s_b2[COUT];
    for (int t = threadIdx.x; t < 18 * 27; t += blockDim.x) s_w1[t] = w1[t];
    if (threadIdx.x < 18) s_b1[threadIdx.x] = b1[threadIdx.x];
    if (threadIdx.x < COUT * CIN * KK) s_w2[threadIdx.x] = w2[threadIdx.x];
    if (threadIdx.x < COUT) s_b2[threadIdx.x] = b2[threadIdx.x];
    __syncthreads();
    const int idx = blockIdx.x * blockDim.x + threadIdx.x;
    if (idx >= BB * HOWO) return;
    const int j = idx % WO;
    const int tmp = idx / WO;
    const int i = tmp % HO;
    const int b = tmp / HO;
    const float* xb = x + (size_t)b * CIN * HW;
    float patch[CIN][3][3];
#pragma unroll
    for (int c = 0; c < CIN; ++c)
#pragma unroll
        for (int r = 0; r < 3; ++r)
#pragma unroll
            for (int s = 0; s < 3; ++s)
                patch[c][r][s] = xb[c * HW + (i + r) * WW + (j + s)];
    float acc0 = s_b2[0], acc1 = s_b2[1], acc2 = s_b2[2];
#pragma unroll
    for (int k = 0; k < KK; ++k) {
        const int ky = k / 3, kx = k % 3;
        float dy = s_b1[2 * k], dx = s_b1[2 * k + 1];
        const float* wy = &s_w1[(2 * k) * 27];
        const float* wx = &s_w1[(2 * k + 1) * 27];
        int t = 0;
#pragma unroll
        for (int c = 0; c < CIN; ++c)
#pragma unroll
            for (int r = 0; r < 3; ++r)
#pragma unroll
                for (int s = 0; s < 3; ++s, ++t) {
                    const float pv = patch[c][r][s];
                    dy += pv * wy[t];
                    dx += pv * wx[t];
                }
        const float sy = (float)(i + ky) + dy;
        const float sx = (float)(j + kx) + dx;
        const float y0f = floorf(sy), x0f = floorf(sx);
        const float fy = sy - y0f, fx = sx - x0f;
        const int y0 = (int)y0f, x0 = (int)x0f;
        float v0 = 0.f, v1 = 0.f, v2 = 0.f;
#pragma unroll
        for (int cy = 0; cy < 2; ++cy) {
            const int iy = y0 + cy;
            const float wyf = cy ? fy : (1.f - fy);
            const bool vy = (iy >= 0) && (iy < HH);
            const int iyc = iy < 0 ? 0 : (iy > HH - 1 ? HH - 1 : iy);
#pragma unroll
            for (int cx = 0; cx < 2; ++cx) {
                const int ix = x0 + cx;
                const float wxf = cx ? fx : (1.f - fx);
                const bool vx = (ix >= 0) && (ix < WW);
                const int ixc = ix < 0 ? 0 : (ix > WW - 1 ? WW - 1 : ix);
                const float wgt = (vy && vx) ? (wyf * wxf) : 0.f;
                const int off = iyc * WW + ixc;
                v0 += wgt * xb[0 * HW + off];
                v1 += wgt * xb[1 * HW + off];
                v2 += wgt * xb[2 * HW + off];
            }
        }
#pragma unroll
        for (int o = 0; o < COUT; ++o) {
            const float c0 = s_w2[(o * CIN + 0) * KK + k];
            const float c1 = s_w2[(o * CIN + 1) * KK + k];
            const float c2 = s_w2[(o * CIN + 2) * KK + k];
            const float contrib = c0 * v0 + c1 * v1 + c2 * v2;
            if (o == 0) acc0 += contrib;
            else if (o == 1) acc1 += contrib;
            else acc2 += contrib;
        }
    }
    float* ob = out + (size_t)b * COUT * HOWO + (size_t)i * WO + j;
    ob[0 * HOWO] = acc0;
    ob[1 * HOWO] = acc1;
    ob[2 * HOWO] = acc2;
}

extern "C" void kernel_launch(void* const* d_in, const int* in_sizes, int n_in,
                              void* d_out, int out_size, void* d_ws, size_t ws_size,
                              hipStream_t stream) {
    const float* x  = (const float*)d_in[0];
    const float* w1 = (const float*)d_in[1];
    const float* b1 = (const float*)d_in[2];
    const float* w2 = (const float*)d_in[3];
    const float* b2 = (const float*)d_in[4];
    float* out = (float*)d_out;

    if (ws_size >= WS_NEED) {
        char* p = (char*)d_ws;
        float4* xp = (float4*)p;
        uint4* offsA = (uint4*)(p + XP_BYTES);
        unsigned int* offsB = (unsigned int*)(p + XP_BYTES + OFFSA_BYTES);
        {
            const int total = BB * PR * PC;
            repack_pad<<<(total + 255) / 256, 256, 0, stream>>>(x, xp);
        }
        {
            const int total = BB * HO * (WO / 2);
            conv1_off<<<(total + 255) / 256, 256, 0, stream>>>(
                xp, w1, b1, offsA, offsB);
        }
        {
            deform_gather<<<(NPX + 255) / 256, 256, 0, stream>>>(
                xp, offsA, offsB, w2, b2, out);
        }
    } else {
        const int total = BB * HOWO;
        deform_fused_kernel<<<(total + 255) / 256, 256, 0, stream>>>(
            x, w1, b1, w2, b2, out);
    }
}